// Round 1
// baseline (355.244 us; speedup 1.0000x reference)
//
#include <hip/hip_runtime.h>
#include <hip/hip_bf16.h>

#define NNODES   524288
#define NGRAPHS  4096
#define HBS      152   // bf16 LDS row stride: 304 B = 19*16 (aligned, 12-bank row shift -> 2-way free)
#define HFS      132   // f32 epilogue row stride: 528 B = 33*16

typedef __attribute__((ext_vector_type(8))) short short8;
typedef __attribute__((ext_vector_type(4))) float f32x4;

static __device__ __forceinline__ unsigned short f2bf(float f) {
    __hip_bfloat16 h = __float2bfloat16(f);
    return *reinterpret_cast<unsigned short*>(&h);
}

// ---- one-time (per launch) weight transpose + bf16 convert: wT[n][k] = w[k][n] ----
__global__ __launch_bounds__(256) void prep_weights(
        const float* __restrict__ w1, const float* __restrict__ w2,
        unsigned short* __restrict__ w1T, unsigned short* __restrict__ w2T) {
    int e   = blockIdx.x * 256 + threadIdx.x;   // 0..32767
    int sel = e >> 14;
    int idx = e & 16383;
    int k = idx >> 7, n = idx & 127;
    const float* src = sel ? w2 : w1;
    unsigned short* dst = sel ? w2T : w1T;
    dst[n * 128 + k] = f2bf(src[k * 128 + n]);
}

// ---- fused phi MLP (3 layers) + segment-sum into g[4096][128] ----
__global__ __launch_bounds__(256) void phi_kernel(
        const float* __restrict__ x, const int* __restrict__ batch,
        const float* __restrict__ w0, const float* __restrict__ b0,
        const unsigned short* __restrict__ w1T, const float* __restrict__ b1,
        const unsigned short* __restrict__ w2T, const float* __restrict__ b2,
        float* __restrict__ g) {
    __shared__ unsigned short hb[128 * HBS];    // 38912 B
    const int tid   = threadIdx.x;
    const int node0 = blockIdx.x * 128;
    const int lane  = tid & 63;
    const int wv    = tid >> 6;
    const int ln15  = lane & 15;
    const int qd    = lane >> 4;
    const int mq    = wv & 1;    // node-quad: waves 0,2 -> nodes 0..63 ; 1,3 -> 64..127
    const int nq    = wv >> 1;   // feat-quad: cols 0..63 / 64..127

    // ---- layer 1: h0 = relu(x @ w0 + b0), K=4 on VALU, bf16 -> hb ----
    {
        const int node = tid >> 1;
        const int fo   = (tid & 1) * 64;
        const float4 xv = *reinterpret_cast<const float4*>(x + (size_t)(node0 + node) * 4);
        #pragma unroll
        for (int f = 0; f < 64; f += 4) {
            const int c = fo + f;
            const float4 bv  = *reinterpret_cast<const float4*>(b0 + c);
            const float4 wv0 = *reinterpret_cast<const float4*>(w0 + c);
            const float4 wv1 = *reinterpret_cast<const float4*>(w0 + 128 + c);
            const float4 wv2 = *reinterpret_cast<const float4*>(w0 + 256 + c);
            const float4 wv3 = *reinterpret_cast<const float4*>(w0 + 384 + c);
            float o0 = bv.x + xv.x*wv0.x + xv.y*wv1.x + xv.z*wv2.x + xv.w*wv3.x;
            float o1 = bv.y + xv.x*wv0.y + xv.y*wv1.y + xv.z*wv2.y + xv.w*wv3.y;
            float o2 = bv.z + xv.x*wv0.z + xv.y*wv1.z + xv.z*wv2.z + xv.w*wv3.z;
            float o3 = bv.w + xv.x*wv0.w + xv.y*wv1.w + xv.z*wv2.w + xv.w*wv3.w;
            ushort4 s = make_ushort4(f2bf(fmaxf(o0, 0.f)), f2bf(fmaxf(o1, 0.f)),
                                     f2bf(fmaxf(o2, 0.f)), f2bf(fmaxf(o3, 0.f)));
            *reinterpret_cast<ushort4*>(&hb[node * HBS + c]) = s;
        }
    }
    __syncthreads();

    // ---- MFMA layer: acc[mt][nt] = hb(tile) @ wT^T ----
    f32x4 acc[4][4];
    auto mfma_layer = [&](const unsigned short* __restrict__ wT) {
        #pragma unroll
        for (int mt = 0; mt < 4; ++mt)
            #pragma unroll
            for (int nt = 0; nt < 4; ++nt)
                acc[mt][nt] = (f32x4){0.f, 0.f, 0.f, 0.f};
        #pragma unroll
        for (int kk = 0; kk < 4; ++kk) {
            const int ko = kk * 32 + qd * 8;
            short8 a[4], b[4];
            #pragma unroll
            for (int mt = 0; mt < 4; ++mt)   // A[m][k]: m = lane&15, k = quad*8+j
                a[mt] = *reinterpret_cast<const short8*>(&hb[(mq*64 + mt*16 + ln15) * HBS + ko]);
            #pragma unroll
            for (int nt = 0; nt < 4; ++nt)   // B[k][n] from wT[n][k]: n = lane&15
                b[nt] = *reinterpret_cast<const short8*>(wT + (nq*64 + nt*16 + ln15) * 128 + ko);
            #pragma unroll
            for (int mt = 0; mt < 4; ++mt)
                #pragma unroll
                for (int nt = 0; nt < 4; ++nt)
                    acc[mt][nt] = __builtin_amdgcn_mfma_f32_16x16x32_bf16(a[mt], b[nt], acc[mt][nt], 0, 0, 0);
        }
    };

    // ---- layer 2 ----
    mfma_layer(w1T);
    __syncthreads();                       // all h0 reads complete before overwrite
    #pragma unroll
    for (int nt = 0; nt < 4; ++nt) {
        const int col  = nq*64 + nt*16 + ln15;
        const float bias = b1[col];
        #pragma unroll
        for (int mt = 0; mt < 4; ++mt) {
            const int rb = mq*64 + mt*16 + qd*4;   // C: row = quad*4 + reg
            #pragma unroll
            for (int r = 0; r < 4; ++r)
                hb[(rb + r) * HBS + col] = f2bf(fmaxf(acc[mt][nt][r] + bias, 0.f));
        }
    }
    __syncthreads();

    // ---- layer 3 (no relu; bias in epilogue) ----
    mfma_layer(w2T);
    __syncthreads();                       // all h1 reads complete before f32 overwrite

    // ---- epilogue: two-pass f32 round-trip + sorted-run segment sum ----
    float* hf = reinterpret_cast<float*>(hb);
    float run = 0.f;
    int gprev = (tid < 128) ? batch[node0] : 0;
    #pragma unroll
    for (int pass = 0; pass < 2; ++pass) {
        if (mq == pass) {
            #pragma unroll
            for (int nt = 0; nt < 4; ++nt) {
                const int col  = nq*64 + nt*16 + ln15;
                const float bias = b2[col];
                #pragma unroll
                for (int mt = 0; mt < 4; ++mt) {
                    const int rb = mt*16 + qd*4;   // local row within this 64-node pass
                    #pragma unroll
                    for (int r = 0; r < 4; ++r)
                        hf[(rb + r) * HFS + col] = acc[mt][nt][r] + bias;
                }
            }
        }
        __syncthreads();
        if (tid < 128) {
            const int nb = node0 + pass * 64;
            for (int i = 0; i < 64; ++i) {
                const int gi = batch[nb + i];      // lane-uniform -> scalar load
                if (gi != gprev) {
                    atomicAdd(&g[(size_t)gprev * 128 + tid], run);
                    run = 0.f;
                    gprev = gi;
                }
                run += hf[i * HFS + tid];
            }
        }
        __syncthreads();
    }
    if (tid < 128) atomicAdd(&g[(size_t)gprev * 128 + tid], run);
}

// ---- F head: 16 graphs per block, fp32 VALU ----
__global__ __launch_bounds__(256) void head_kernel(
        const float* __restrict__ g,
        const float* __restrict__ fw0, const float* __restrict__ fb0,
        const float* __restrict__ fw1, const float* __restrict__ fb1,
        const float* __restrict__ fw2, const float* __restrict__ fb2,
        float* __restrict__ out) {
    __shared__ float gT[128 * 20];   // gT[k][i], pad 20 -> 80 B rows (16B aligned)
    __shared__ float hT[256 * 20];
    const int tid = threadIdx.x;
    const int g0  = blockIdx.x * 16;
    {
        const int i  = tid >> 4;
        const int k0 = (tid & 15) * 8;
        const float* src = g + (size_t)(g0 + i) * 128 + k0;
        const f32x4 v0 = *reinterpret_cast<const f32x4*>(src);
        const f32x4 v1 = *reinterpret_cast<const f32x4*>(src + 4);
        #pragma unroll
        for (int j = 0; j < 4; ++j) {
            gT[(k0 + j) * 20 + i]     = v0[j];
            gT[(k0 + 4 + j) * 20 + i] = v1[j];
        }
    }
    __syncthreads();
    float acc[16];
    #pragma unroll
    for (int i = 0; i < 16; ++i) acc[i] = fb0[tid];
    for (int k = 0; k < 128; ++k) {
        const float w = fw0[k * 256 + tid];
        const f32x4* row = reinterpret_cast<const f32x4*>(&gT[k * 20]);
        #pragma unroll
        for (int q = 0; q < 4; ++q) {
            const f32x4 rv = row[q];
            #pragma unroll
            for (int j = 0; j < 4; ++j) acc[q*4 + j] += rv[j] * w;
        }
    }
    #pragma unroll
    for (int q = 0; q < 4; ++q) {
        f32x4 sv;
        #pragma unroll
        for (int j = 0; j < 4; ++j) sv[j] = fmaxf(acc[q*4 + j], 0.f);
        *reinterpret_cast<f32x4*>(&hT[tid * 20 + q*4]) = sv;
    }
    __syncthreads();
    #pragma unroll
    for (int i = 0; i < 16; ++i) acc[i] = fb1[tid];
    for (int k = 0; k < 256; ++k) {
        const float w = fw1[k * 256 + tid];
        const f32x4* row = reinterpret_cast<const f32x4*>(&hT[k * 20]);
        #pragma unroll
        for (int q = 0; q < 4; ++q) {
            const f32x4 rv = row[q];
            #pragma unroll
            for (int j = 0; j < 4; ++j) acc[q*4 + j] += rv[j] * w;
        }
    }
    __syncthreads();   // all h1 reads done before overwrite
    #pragma unroll
    for (int q = 0; q < 4; ++q) {
        f32x4 sv;
        #pragma unroll
        for (int j = 0; j < 4; ++j) sv[j] = fmaxf(acc[q*4 + j], 0.f);
        *reinterpret_cast<f32x4*>(&hT[tid * 20 + q*4]) = sv;
    }
    __syncthreads();
    {
        const int i = tid >> 4;        // graph 0..15
        const int s = (tid >> 3) & 1;  // score dim
        const int p = tid & 7;         // k partition
        float sum = 0.f;
        for (int k = p * 32; k < p * 32 + 32; ++k)
            sum += hT[k * 20 + i] * fw2[k * 2 + s];
        sum += __shfl_down(sum, 4);
        sum += __shfl_down(sum, 2);
        sum += __shfl_down(sum, 1);
        if (p == 0) out[(g0 + i) * 2 + s] = sum + fb2[s];
    }
}

extern "C" void kernel_launch(void* const* d_in, const int* in_sizes, int n_in,
                              void* d_out, int out_size, void* d_ws, size_t ws_size,
                              hipStream_t stream) {
    const float* x   = (const float*)d_in[0];
    // d_in[1] edge_index: mathematically dead (update() ignores aggr_out) — never read
    const int*   batch = (const int*)d_in[2];
    const float* w0  = (const float*)d_in[3];
    const float* b0  = (const float*)d_in[4];
    const float* w1  = (const float*)d_in[5];
    const float* b1  = (const float*)d_in[6];
    const float* w2  = (const float*)d_in[7];
    const float* b2  = (const float*)d_in[8];
    const float* fw0 = (const float*)d_in[9];
    const float* fb0 = (const float*)d_in[10];
    const float* fw1 = (const float*)d_in[11];
    const float* fb1 = (const float*)d_in[12];
    const float* fw2 = (const float*)d_in[13];
    const float* fb2 = (const float*)d_in[14];
    float* out = (float*)d_out;

    float* g = (float*)d_ws;                                   // 4096*128 f32 = 2 MB
    unsigned short* w1T = (unsigned short*)((char*)d_ws + (size_t)NGRAPHS * 128 * 4);
    unsigned short* w2T = w1T + 128 * 128;

    hipMemsetAsync(g, 0, (size_t)NGRAPHS * 128 * sizeof(float), stream);
    prep_weights<<<128, 256, 0, stream>>>(w1, w2, w1T, w2T);
    phi_kernel<<<NNODES / 128, 256, 0, stream>>>(x, batch, w0, b0, w1T, b1, w2T, b2, g);
    head_kernel<<<NGRAPHS / 16, 256, 0, stream>>>(g, fw0, fb0, fw1, fb1, fw2, fb2, out);
}

// Round 2
// 283.924 us; speedup vs baseline: 1.2512x; 1.2512x over previous
//
#include <hip/hip_runtime.h>
#include <hip/hip_bf16.h>

#define NNODES   524288
#define NGRAPHS  4096
#define HBS      136   // bf16 LDS row stride (shorts): 272 B, 16B-aligned rows
#define HFS      132   // f32 epilogue row stride (floats)
#define GTS      20    // head LDS row stride (floats)

typedef __attribute__((ext_vector_type(8))) short short8;
typedef __attribute__((ext_vector_type(4))) float f32x4;

static __device__ __forceinline__ unsigned short f2bf(float f) {
    __hip_bfloat16 h = __float2bfloat16(f);
    return *reinterpret_cast<unsigned short*>(&h);
}

// ---- one-time (per launch): bf16 weight transposes ----
__global__ __launch_bounds__(256) void prep_weights(
        const float* __restrict__ w0, const float* __restrict__ w1,
        const float* __restrict__ w2,
        unsigned short* __restrict__ w0c, unsigned short* __restrict__ w1T,
        unsigned short* __restrict__ w2T) {
    int e = blockIdx.x * 256 + threadIdx.x;
    if (e < 16384) {
        int k = e >> 7, n = e & 127;
        w1T[n * 128 + k] = f2bf(w1[e]);
    } else if (e < 32768) {
        int i = e - 16384;
        int k = i >> 7, n = i & 127;
        w2T[n * 128 + k] = f2bf(w2[i]);
    } else if (e < 33280) {
        int i = e - 32768;
        int k = i >> 7, n = i & 127;      // w0 is [4][128]
        w0c[n * 4 + k] = f2bf(w0[i]);
    }
}

// ---- fused phi MLP (3 MFMA layers) + parallel segmented sum into g ----
__global__ __launch_bounds__(256) void phi_kernel(
        const float* __restrict__ x, const int* __restrict__ batch,
        const unsigned short* __restrict__ w0c, const float* __restrict__ b0,
        const unsigned short* __restrict__ w1T, const float* __restrict__ b1,
        const unsigned short* __restrict__ w2T, const float* __restrict__ b2,
        float* __restrict__ g) {
    __shared__ unsigned short hb[128 * HBS];     // 34816 B, reused as f32 [64][HFS]
    __shared__ int gid[128];
    __shared__ unsigned long long bmask[2];
    __shared__ int rstart[130];
    __shared__ int nruns_s;

    const int tid   = threadIdx.x;
    const int node0 = blockIdx.x * 128;
    const int lane  = tid & 63;
    const int wv    = tid >> 6;
    const int ln15  = lane & 15;
    const int qd    = lane >> 4;
    const int mq    = wv & 1;    // node half
    const int nq    = wv >> 1;   // feature half

    // stage graph ids (parallel, once)
    if (tid < 128) gid[tid] = batch[node0 + tid];

    // ---- layer-1 fragments: x (K=4 zero-padded to 32) and w0c ----
    f32x4 acc[4][4];
    #pragma unroll
    for (int mt = 0; mt < 4; ++mt)
        #pragma unroll
        for (int nt = 0; nt < 4; ++nt)
            acc[mt][nt] = (f32x4){0.f, 0.f, 0.f, 0.f};

    short8 xa[4], wb[4];
    #pragma unroll
    for (int i = 0; i < 4; ++i) {
        xa[i] = (short8){0,0,0,0,0,0,0,0};
        wb[i] = (short8){0,0,0,0,0,0,0,0};
    }
    if (qd == 0) {   // only k=0..3 (quad 0) carries data; other quads supply K-pad zeros
        #pragma unroll
        for (int mt = 0; mt < 4; ++mt) {
            const float4 xv = *reinterpret_cast<const float4*>(
                x + (size_t)(node0 + mq*64 + mt*16 + ln15) * 4);
            xa[mt][0] = (short)f2bf(xv.x); xa[mt][1] = (short)f2bf(xv.y);
            xa[mt][2] = (short)f2bf(xv.z); xa[mt][3] = (short)f2bf(xv.w);
        }
        #pragma unroll
        for (int nt = 0; nt < 4; ++nt) {
            const ushort4 wv4 = *reinterpret_cast<const ushort4*>(
                w0c + (nq*64 + nt*16 + ln15) * 4);
            wb[nt][0] = (short)wv4.x; wb[nt][1] = (short)wv4.y;
            wb[nt][2] = (short)wv4.z; wb[nt][3] = (short)wv4.w;
        }
    }

    __syncthreads();   // gid visible

    // run-boundary detection (overlaps with layer-1 MFMA)
    unsigned long long mymask = 0ull;
    bool myflag = false;
    if (wv < 2) {
        const int i = wv*64 + lane;
        myflag = (i == 0) || (gid[i] != gid[i-1]);
        mymask = __ballot(myflag);
        if (lane == 0) bmask[wv] = mymask;
    }

    // ---- layer-1 MFMA (16 MFMAs) ----
    #pragma unroll
    for (int mt = 0; mt < 4; ++mt)
        #pragma unroll
        for (int nt = 0; nt < 4; ++nt)
            acc[mt][nt] = __builtin_amdgcn_mfma_f32_16x16x32_bf16(xa[mt], wb[nt], acc[mt][nt], 0, 0, 0);

    __syncthreads();   // bmask visible

    if (wv < 2 && myflag) {
        const int i = wv*64 + lane;
        const int rank = (wv ? __popcll(bmask[0]) : 0)
                       + __popcll(mymask & ((1ull << lane) - 1ull));
        rstart[rank] = i;
    }
    if (tid == 0) {
        const int nr = __popcll(bmask[0]) + __popcll(bmask[1]);
        nruns_s = nr;
        rstart[nr] = 128;
    }

    // layer-1 writeback: bias + relu -> bf16 hb (C layout: row=qd*4+r, col=ln15)
    #pragma unroll
    for (int nt = 0; nt < 4; ++nt) {
        const int col = nq*64 + nt*16 + ln15;
        const float bias = b0[col];
        #pragma unroll
        for (int mt = 0; mt < 4; ++mt) {
            const int rb = mq*64 + mt*16 + qd*4;
            #pragma unroll
            for (int r = 0; r < 4; ++r)
                hb[(rb + r) * HBS + col] = f2bf(fmaxf(acc[mt][nt][r] + bias, 0.f));
        }
    }
    __syncthreads();

    // ---- MFMA layer over hb tile ----
    auto mfma_layer = [&](const unsigned short* __restrict__ wT) {
        #pragma unroll
        for (int mt = 0; mt < 4; ++mt)
            #pragma unroll
            for (int nt = 0; nt < 4; ++nt)
                acc[mt][nt] = (f32x4){0.f, 0.f, 0.f, 0.f};
        #pragma unroll
        for (int kk = 0; kk < 4; ++kk) {
            const int ko = kk*32 + qd*8;
            short8 a[4], b[4];
            #pragma unroll
            for (int mt = 0; mt < 4; ++mt)
                a[mt] = *reinterpret_cast<const short8*>(&hb[(mq*64 + mt*16 + ln15) * HBS + ko]);
            #pragma unroll
            for (int nt = 0; nt < 4; ++nt)
                b[nt] = *reinterpret_cast<const short8*>(wT + (nq*64 + nt*16 + ln15) * 128 + ko);
            #pragma unroll
            for (int mt = 0; mt < 4; ++mt)
                #pragma unroll
                for (int nt = 0; nt < 4; ++nt)
                    acc[mt][nt] = __builtin_amdgcn_mfma_f32_16x16x32_bf16(a[mt], b[nt], acc[mt][nt], 0, 0, 0);
        }
    };

    // ---- layer 2 ----
    mfma_layer(w1T);
    __syncthreads();
    #pragma unroll
    for (int nt = 0; nt < 4; ++nt) {
        const int col = nq*64 + nt*16 + ln15;
        const float bias = b1[col];
        #pragma unroll
        for (int mt = 0; mt < 4; ++mt) {
            const int rb = mq*64 + mt*16 + qd*4;
            #pragma unroll
            for (int r = 0; r < 4; ++r)
                hb[(rb + r) * HBS + col] = f2bf(fmaxf(acc[mt][nt][r] + bias, 0.f));
        }
    }
    __syncthreads();

    // ---- layer 3 ----
    mfma_layer(w2T);
    __syncthreads();   // all hb reads complete before f32 reuse

    // ---- epilogue: two-pass f32 round-trip + PARALLEL segmented reduction ----
    float* hf = reinterpret_cast<float*>(hb);    // [64][HFS]
    const int nr = nruns_s;
    #pragma unroll
    for (int pass = 0; pass < 2; ++pass) {
        if (mq == pass) {
            #pragma unroll
            for (int nt = 0; nt < 4; ++nt) {
                const int col = nq*64 + nt*16 + ln15;
                const float bias = b2[col];
                #pragma unroll
                for (int mt = 0; mt < 4; ++mt) {
                    const int rb = mt*16 + qd*4;
                    #pragma unroll
                    for (int r = 0; r < 4; ++r)
                        hf[(rb + r) * HFS + col] = acc[mt][nt][r] + bias;
                }
            }
        }
        __syncthreads();
        {
            const int col = tid & 127;
            const int h   = tid >> 7;
            const int wlo = pass * 64, whi = wlo + 64;
            for (int r = 0; r < nr; ++r) {               // nr, rstart block-uniform
                const int s = rstart[r], e = rstart[r+1];
                if (e <= wlo || s >= whi) continue;      // uniform branch
                const int ss = (s > wlo ? s : wlo);
                const int ee = (e < whi ? e : whi);
                float part = 0.f;
                for (int i = ss + h; i < ee; i += 2)     // independent LDS reads
                    part += hf[(i - wlo) * HFS + col];
                if (ss + h < ee)
                    atomicAdd(&g[(size_t)gid[s] * 128 + col], part);
            }
        }
        __syncthreads();
    }
}

// ---- F head: 16 graphs/block, thread = 4 cols x 4 graphs, fp32 VALU ----
__global__ __launch_bounds__(256) void head_kernel(
        const float* __restrict__ g,
        const float* __restrict__ fw0, const float* __restrict__ fb0,
        const float* __restrict__ fw1, const float* __restrict__ fb1,
        const float* __restrict__ fw2, const float* __restrict__ fb2,
        float* __restrict__ out) {
    __shared__ float gT[128 * GTS];   // [k][graph]
    __shared__ float hT[256 * GTS];   // [k][graph]
    const int tid = threadIdx.x;
    const int g0  = blockIdx.x * 16;
    const int wv  = tid >> 6;         // wave -> graph group (4 graphs)
    const int c0  = (tid & 63) * 4;   // 4 output cols per thread

    // stage + transpose g tile: [16][128] -> gT[k][graph]
    {
        const int gi = tid >> 4;
        const int k0 = (tid & 15) * 8;
        const float* src = g + (size_t)(g0 + gi) * 128 + k0;
        const float4 v0 = *reinterpret_cast<const float4*>(src);
        const float4 v1 = *reinterpret_cast<const float4*>(src + 4);
        gT[(k0+0)*GTS + gi] = v0.x; gT[(k0+1)*GTS + gi] = v0.y;
        gT[(k0+2)*GTS + gi] = v0.z; gT[(k0+3)*GTS + gi] = v0.w;
        gT[(k0+4)*GTS + gi] = v1.x; gT[(k0+5)*GTS + gi] = v1.y;
        gT[(k0+6)*GTS + gi] = v1.z; gT[(k0+7)*GTS + gi] = v1.w;
    }
    __syncthreads();

    float acc[4][4];   // [ci][gj]
    #pragma unroll
    for (int ci = 0; ci < 4; ++ci)
        #pragma unroll
        for (int gj = 0; gj < 4; ++gj) acc[ci][gj] = 0.f;

    // layer 1: h1 = relu(g @ fw0 + fb0)
    #pragma unroll 2
    for (int k = 0; k < 128; ++k) {
        const float4 w = *reinterpret_cast<const float4*>(fw0 + k*256 + c0);
        const f32x4 gv = *reinterpret_cast<const f32x4*>(&gT[k*GTS + wv*4]);  // broadcast
        const float wc[4] = {w.x, w.y, w.z, w.w};
        #pragma unroll
        for (int ci = 0; ci < 4; ++ci)
            #pragma unroll
            for (int gj = 0; gj < 4; ++gj)
                acc[ci][gj] += wc[ci] * gv[gj];
    }
    #pragma unroll
    for (int ci = 0; ci < 4; ++ci) {
        const float bias = fb0[c0 + ci];
        f32x4 hv;
        #pragma unroll
        for (int gj = 0; gj < 4; ++gj) hv[gj] = fmaxf(acc[ci][gj] + bias, 0.f);
        *reinterpret_cast<f32x4*>(&hT[(c0 + ci)*GTS + wv*4]) = hv;
    }
    __syncthreads();

    // layer 2: h2 = relu(h1 @ fw1 + fb1) — kept in registers
    #pragma unroll
    for (int ci = 0; ci < 4; ++ci)
        #pragma unroll
        for (int gj = 0; gj < 4; ++gj) acc[ci][gj] = 0.f;
    #pragma unroll 2
    for (int k = 0; k < 256; ++k) {
        const float4 w = *reinterpret_cast<const float4*>(fw1 + k*256 + c0);
        const f32x4 hv = *reinterpret_cast<const f32x4*>(&hT[k*GTS + wv*4]);  // broadcast
        const float wc[4] = {w.x, w.y, w.z, w.w};
        #pragma unroll
        for (int ci = 0; ci < 4; ++ci)
            #pragma unroll
            for (int gj = 0; gj < 4; ++gj)
                acc[ci][gj] += wc[ci] * hv[gj];
    }

    // layer 3 folded into register partials + wave reduction (cols span wave)
    float p[4][2];
    #pragma unroll
    for (int gj = 0; gj < 4; ++gj) { p[gj][0] = 0.f; p[gj][1] = 0.f; }
    #pragma unroll
    for (int ci = 0; ci < 4; ++ci) {
        const float bias = fb1[c0 + ci];
        const float w2a = fw2[(c0 + ci)*2 + 0];
        const float w2b = fw2[(c0 + ci)*2 + 1];
        #pragma unroll
        for (int gj = 0; gj < 4; ++gj) {
            const float h2 = fmaxf(acc[ci][gj] + bias, 0.f);
            p[gj][0] += h2 * w2a;
            p[gj][1] += h2 * w2b;
        }
    }
    #pragma unroll
    for (int gj = 0; gj < 4; ++gj)
        #pragma unroll
        for (int s = 0; s < 2; ++s) {
            float v = p[gj][s];
            #pragma unroll
            for (int off = 32; off > 0; off >>= 1) v += __shfl_down(v, off);
            if ((tid & 63) == 0)
                out[(size_t)(g0 + wv*4 + gj)*2 + s] = v + fb2[s];
        }
}

extern "C" void kernel_launch(void* const* d_in, const int* in_sizes, int n_in,
                              void* d_out, int out_size, void* d_ws, size_t ws_size,
                              hipStream_t stream) {
    const float* x   = (const float*)d_in[0];
    // d_in[1] edge_index: mathematically dead (update() ignores aggr_out) — never read
    const int*   batch = (const int*)d_in[2];
    const float* w0  = (const float*)d_in[3];
    const float* b0  = (const float*)d_in[4];
    const float* w1  = (const float*)d_in[5];
    const float* b1  = (const float*)d_in[6];
    const float* w2  = (const float*)d_in[7];
    const float* b2  = (const float*)d_in[8];
    const float* fw0 = (const float*)d_in[9];
    const float* fb0 = (const float*)d_in[10];
    const float* fw1 = (const float*)d_in[11];
    const float* fb1 = (const float*)d_in[12];
    const float* fw2 = (const float*)d_in[13];
    const float* fb2 = (const float*)d_in[14];
    float* out = (float*)d_out;

    float* g = (float*)d_ws;                                        // 2 MB
    unsigned short* w1T = (unsigned short*)((char*)d_ws + (size_t)NGRAPHS * 128 * 4);
    unsigned short* w2T = w1T + 128 * 128;
    unsigned short* w0c = w2T + 128 * 128;                          // 1 KB

    hipMemsetAsync(g, 0, (size_t)NGRAPHS * 128 * sizeof(float), stream);
    prep_weights<<<130, 256, 0, stream>>>(w0, w1, w2, w0c, w1T, w2T);
    phi_kernel<<<NNODES / 128, 256, 0, stream>>>(x, batch, w0c, b0, w1T, b1, w2T, b2, g);
    head_kernel<<<NGRAPHS / 16, 256, 0, stream>>>(g, fw0, fb0, fw1, fb1, fw2, fb2, out);
}

// Round 3
// 221.356 us; speedup vs baseline: 1.6049x; 1.2827x over previous
//
#include <hip/hip_runtime.h>
#include <hip/hip_bf16.h>

#define NNODES   524288
#define NGRAPHS  4096
#define HBS      136   // bf16 LDS row stride (shorts): 272 B (16B-aligned rows)
#define GS       12    // head LDS row stride (floats): 48 B (16B-aligned)

typedef __attribute__((ext_vector_type(8))) short short8;
typedef __attribute__((ext_vector_type(4))) float f32x4;

static __device__ __forceinline__ unsigned short f2bf(float f) {
    __hip_bfloat16 h = __float2bfloat16(f);
    return *reinterpret_cast<unsigned short*>(&h);
}

// ---- one-time: bf16 weight transposes (+ K-padded w0) ----
__global__ __launch_bounds__(256) void prep_weights(
        const float* __restrict__ w0, const float* __restrict__ w1,
        const float* __restrict__ w2,
        unsigned short* __restrict__ w0p, unsigned short* __restrict__ w1T,
        unsigned short* __restrict__ w2T) {
    int e = blockIdx.x * 256 + threadIdx.x;
    if (e < 16384) {
        int k = e >> 7, n = e & 127;
        w1T[n * 128 + k] = f2bf(w1[e]);
    } else if (e < 32768) {
        int i = e - 16384;
        int k = i >> 7, n = i & 127;
        w2T[n * 128 + k] = f2bf(w2[i]);
    } else if (e < 36864) {
        int i = e - 32768;                 // 0..4095 -> w0p[128][32], zero-padded K
        int n = i >> 5, k = i & 31;
        w0p[n * 32 + k] = (k < 4) ? f2bf(w0[k * 128 + n]) : (unsigned short)0;
    }
}

// ---- fused phi MLP: 1 wave per block, 64 nodes, ZERO barriers ----
__global__ __launch_bounds__(64, 2) void phi_kernel(
        const float* __restrict__ x, const int* __restrict__ batch,
        const unsigned short* __restrict__ w0p, const float* __restrict__ b0,
        const unsigned short* __restrict__ w1T, const float* __restrict__ b1,
        const unsigned short* __restrict__ w2T, const float* __restrict__ b2,
        float* __restrict__ g) {
    __shared__ __align__(16) unsigned short hb[64 * HBS];   // 17408 B, wave-private
    const int lane = threadIdx.x;
    const int n0   = blockIdx.x * 64;
    const int ln15 = lane & 15;
    const int qd   = lane >> 4;

    // graph ids + run-start mask (all in registers)
    const int gi = batch[n0 + lane];
    const int gp = __shfl_up(gi, 1);
    const unsigned long long mask = __ballot((lane == 0) || (gi != gp));

    // ---- layer 1: A = x rows (K=4 zero-padded to 32), B = w0p ----
    short8 xa[4];
    #pragma unroll
    for (int mt = 0; mt < 4; ++mt) {
        const float4 xv = *reinterpret_cast<const float4*>(
            x + (size_t)(n0 + mt*16 + ln15) * 4);
        short8 v = (short8){0,0,0,0,0,0,0,0};
        if (qd == 0) {
            v[0] = (short)f2bf(xv.x); v[1] = (short)f2bf(xv.y);
            v[2] = (short)f2bf(xv.z); v[3] = (short)f2bf(xv.w);
        }
        xa[mt] = v;
    }

    f32x4 acc[4][8];   // 64 rows x 128 cols / 64 lanes = 128 f32
    #pragma unroll
    for (int mt = 0; mt < 4; ++mt)
        #pragma unroll
        for (int nt = 0; nt < 8; ++nt) acc[mt][nt] = (f32x4){0.f,0.f,0.f,0.f};

    #pragma unroll
    for (int nt = 0; nt < 8; ++nt) {
        const short8 b = *reinterpret_cast<const short8*>(
            w0p + (nt*16 + ln15) * 32 + qd*8);
        #pragma unroll
        for (int mt = 0; mt < 4; ++mt)
            acc[mt][nt] = __builtin_amdgcn_mfma_f32_16x16x32_bf16(xa[mt], b, acc[mt][nt], 0, 0, 0);
    }
    // writeback h0 (bias+relu, bf16). C: col=ln15, row=qd*4+r
    #pragma unroll
    for (int nt = 0; nt < 8; ++nt) {
        const int col = nt*16 + ln15;
        const float bias = b0[col];
        #pragma unroll
        for (int mt = 0; mt < 4; ++mt) {
            const int rb = mt*16 + qd*4;
            #pragma unroll
            for (int r = 0; r < 4; ++r)
                hb[(rb + r) * HBS + col] = f2bf(fmaxf(acc[mt][nt][r] + bias, 0.f));
        }
    }

    // ---- layers 2 & 3 (wave-private LDS; in-place safe: full read precedes wb) ----
    #pragma unroll 1
    for (int layer = 0; layer < 2; ++layer) {
        const unsigned short* wT = layer ? w2T : w1T;
        #pragma unroll
        for (int mt = 0; mt < 4; ++mt)
            #pragma unroll
            for (int nt = 0; nt < 8; ++nt) acc[mt][nt] = (f32x4){0.f,0.f,0.f,0.f};
        #pragma unroll
        for (int kk = 0; kk < 4; ++kk) {
            const int ko = kk*32 + qd*8;
            short8 a[4];
            #pragma unroll
            for (int mt = 0; mt < 4; ++mt)
                a[mt] = *reinterpret_cast<const short8*>(&hb[(mt*16 + ln15) * HBS + ko]);
            #pragma unroll
            for (int nt = 0; nt < 8; ++nt) {
                const short8 b = *reinterpret_cast<const short8*>(
                    wT + (nt*16 + ln15) * 128 + ko);
                #pragma unroll
                for (int mt = 0; mt < 4; ++mt)
                    acc[mt][nt] = __builtin_amdgcn_mfma_f32_16x16x32_bf16(a[mt], b, acc[mt][nt], 0, 0, 0);
            }
        }
        if (layer == 0) {   // writeback h1
            #pragma unroll
            for (int nt = 0; nt < 8; ++nt) {
                const int col = nt*16 + ln15;
                const float bias = b1[col];
                #pragma unroll
                for (int mt = 0; mt < 4; ++mt) {
                    const int rb = mt*16 + qd*4;
                    #pragma unroll
                    for (int r = 0; r < 4; ++r)
                        hb[(rb + r) * HBS + col] = f2bf(fmaxf(acc[mt][nt][r] + bias, 0.f));
                }
            }
        }
    }

    // ---- epilogue: register-space segmented sum, atomics into g ----
    float b2v[8];
    #pragma unroll
    for (int nt = 0; nt < 8; ++nt) b2v[nt] = b2[nt*16 + ln15];

    unsigned long long rem = mask & (mask - 1);   // drop run-start at 0
    int s = 0;
    while (true) {
        const int e = rem ? (int)__builtin_ctzll(rem) : 64;
        const int grun = __shfl(gi, s);            // wave-uniform
        const float cnt = (float)(e - s);
        float* gdst = g + (size_t)grun * 128;
        #pragma unroll
        for (int nt = 0; nt < 8; ++nt) {
            float val = 0.f;
            #pragma unroll
            for (int mt = 0; mt < 4; ++mt) {
                #pragma unroll
                for (int r = 0; r < 4; ++r) {
                    const int row = mt*16 + qd*4 + r;
                    const float inc = (row >= s && row < e) ? 1.f : 0.f;
                    val = fmaf(acc[mt][nt][r], inc, val);
                }
            }
            val += __shfl_xor(val, 16);
            val += __shfl_xor(val, 32);
            if (qd == 0)
                atomicAdd(gdst + nt*16 + ln15, fmaf(cnt, b2v[nt], val));
        }
        if (!rem) break;
        s = e;
        rem &= rem - 1;
    }
}

// ---- F head: fused 3 layers, 8 graphs/block, 512 blocks ----
__global__ __launch_bounds__(256) void head_kernel(
        const float* __restrict__ g,
        const float* __restrict__ fw0, const float* __restrict__ fb0,
        const float* __restrict__ fw1, const float* __restrict__ fb1,
        const float* __restrict__ fw2, const float* __restrict__ fb2,
        float* __restrict__ out) {
    __shared__ float gS[128 * GS];    // [k][graph]
    __shared__ float h1T[256 * GS];   // [k][graph]
    __shared__ float red[4][16];
    const int tid = threadIdx.x;
    const int g0  = blockIdx.x * 8;

    {   // stage g tile transposed
        const int gr = tid >> 5, k0 = (tid & 31) * 4;
        const float4 v = *reinterpret_cast<const float4*>(
            g + (size_t)(g0 + gr) * 128 + k0);
        gS[(k0+0)*GS + gr] = v.x; gS[(k0+1)*GS + gr] = v.y;
        gS[(k0+2)*GS + gr] = v.z; gS[(k0+3)*GS + gr] = v.w;
    }
    __syncthreads();

    float a1[8];
    #pragma unroll
    for (int i = 0; i < 8; ++i) a1[i] = 0.f;
    #pragma unroll 4
    for (int k = 0; k < 128; ++k) {
        const float w = fw0[k * 256 + tid];
        const f32x4 v0 = *reinterpret_cast<const f32x4*>(&gS[k*GS]);
        const f32x4 v1 = *reinterpret_cast<const f32x4*>(&gS[k*GS + 4]);
        #pragma unroll
        for (int j = 0; j < 4; ++j) {
            a1[j]     = fmaf(v0[j], w, a1[j]);
            a1[4 + j] = fmaf(v1[j], w, a1[4 + j]);
        }
    }
    {
        const float bb = fb0[tid];
        f32x4 s0, s1;
        #pragma unroll
        for (int j = 0; j < 4; ++j) {
            s0[j] = fmaxf(a1[j] + bb, 0.f);
            s1[j] = fmaxf(a1[4 + j] + bb, 0.f);
        }
        *reinterpret_cast<f32x4*>(&h1T[tid*GS])     = s0;
        *reinterpret_cast<f32x4*>(&h1T[tid*GS + 4]) = s1;
    }
    __syncthreads();

    float a2[8];
    #pragma unroll
    for (int i = 0; i < 8; ++i) a2[i] = 0.f;
    #pragma unroll 4
    for (int k = 0; k < 256; ++k) {
        const float w = fw1[k * 256 + tid];
        const f32x4 v0 = *reinterpret_cast<const f32x4*>(&h1T[k*GS]);
        const f32x4 v1 = *reinterpret_cast<const f32x4*>(&h1T[k*GS + 4]);
        #pragma unroll
        for (int j = 0; j < 4; ++j) {
            a2[j]     = fmaf(v0[j], w, a2[j]);
            a2[4 + j] = fmaf(v1[j], w, a2[4 + j]);
        }
    }

    // layer 3 folded: p[graph*2 + s]
    float p[16];
    {
        const float bb  = fb1[tid];
        const float w2a = fw2[tid*2 + 0];
        const float w2b = fw2[tid*2 + 1];
        #pragma unroll
        for (int i = 0; i < 8; ++i) {
            const float h2 = fmaxf(a2[i] + bb, 0.f);
            p[i*2 + 0] = h2 * w2a;
            p[i*2 + 1] = h2 * w2b;
        }
    }
    #pragma unroll
    for (int i = 0; i < 16; ++i) {
        float v = p[i];
        v += __shfl_xor(v, 32); v += __shfl_xor(v, 16); v += __shfl_xor(v, 8);
        v += __shfl_xor(v, 4);  v += __shfl_xor(v, 2);  v += __shfl_xor(v, 1);
        p[i] = v;
    }
    if ((tid & 63) == 0) {
        #pragma unroll
        for (int i = 0; i < 16; ++i) red[tid >> 6][i] = p[i];
    }
    __syncthreads();
    if (tid < 16)
        out[g0*2 + tid] = red[0][tid] + red[1][tid] + red[2][tid] + red[3][tid]
                        + fb2[tid & 1];
}

extern "C" void kernel_launch(void* const* d_in, const int* in_sizes, int n_in,
                              void* d_out, int out_size, void* d_ws, size_t ws_size,
                              hipStream_t stream) {
    const float* x   = (const float*)d_in[0];
    // d_in[1] edge_index: mathematically dead (update() ignores aggr_out) — never read
    const int*   batch = (const int*)d_in[2];
    const float* w0  = (const float*)d_in[3];
    const float* b0  = (const float*)d_in[4];
    const float* w1  = (const float*)d_in[5];
    const float* b1  = (const float*)d_in[6];
    const float* w2  = (const float*)d_in[7];
    const float* b2  = (const float*)d_in[8];
    const float* fw0 = (const float*)d_in[9];
    const float* fb0 = (const float*)d_in[10];
    const float* fw1 = (const float*)d_in[11];
    const float* fb1 = (const float*)d_in[12];
    const float* fw2 = (const float*)d_in[13];
    const float* fb2 = (const float*)d_in[14];
    float* out = (float*)d_out;

    float* g = (float*)d_ws;                                        // 2 MB
    unsigned short* w1T = (unsigned short*)((char*)d_ws + (size_t)NGRAPHS * 128 * 4);
    unsigned short* w2T = w1T + 128 * 128;
    unsigned short* w0p = w2T + 128 * 128;                          // 8 KB padded

    hipMemsetAsync(g, 0, (size_t)NGRAPHS * 128 * sizeof(float), stream);
    prep_weights<<<144, 256, 0, stream>>>(w0, w1, w2, w0p, w1T, w2T);
    phi_kernel<<<NNODES / 64, 64, 0, stream>>>(x, batch, w0p, b0, w1T, b1, w2T, b2, g);
    head_kernel<<<NGRAPHS / 8, 256, 0, stream>>>(g, fw0, fb0, fw1, fb1, fw2, fb2, out);
}

// Round 5
// 213.932 us; speedup vs baseline: 1.6606x; 1.0347x over previous
//
#include <hip/hip_runtime.h>
#include <hip/hip_bf16.h>

#define NNODES   524288
#define NGRAPHS  4096
#define GS       12    // head LDS row stride (floats)

typedef __attribute__((ext_vector_type(8)))  short short8;
typedef __attribute__((ext_vector_type(4)))  float f32x4;
typedef __attribute__((ext_vector_type(16))) float f32x16;

static __device__ __forceinline__ unsigned short f2bf(float f) {
    __hip_bfloat16 h = __float2bfloat16(f);
    return *reinterpret_cast<unsigned short*>(&h);
}

// swizzled LDS offset (shorts): node-row 128 shorts, 16B chunks XOR-permuted
static __device__ __forceinline__ int swz(int node, int chunk) {
    return node * 128 + ((chunk ^ (node & 15)) << 3);
}

// ---- one-time: bf16 weight transposes. wT[of][k] = w[k][of]; w0p[of][16] K-padded ----
__global__ __launch_bounds__(256) void prep_weights(
        const float* __restrict__ w0, const float* __restrict__ w1,
        const float* __restrict__ w2,
        unsigned short* __restrict__ w0p, unsigned short* __restrict__ w1T,
        unsigned short* __restrict__ w2T) {
    int e = blockIdx.x * 256 + threadIdx.x;
    if (e < 16384) {
        int k = e >> 7, n = e & 127;
        w1T[n * 128 + k] = f2bf(w1[e]);
    } else if (e < 32768) {
        int i = e - 16384;
        int k = i >> 7, n = i & 127;
        w2T[n * 128 + k] = f2bf(w2[i]);
    } else if (e < 34816) {
        int i = e - 32768;                 // w0p[128][16], K=4 zero-padded to 16
        int of = i >> 4, k = i & 15;
        w0p[i] = (k < 4) ? f2bf(w0[k * 128 + of]) : (unsigned short)0;
    }
}

// ---- fused phi MLP: 1 wave/block, 64 nodes, zero barriers, 32x32x16 MFMA ----
__global__ __launch_bounds__(64, 2) void phi_kernel(
        const float* __restrict__ x, const int* __restrict__ batch,
        const unsigned short* __restrict__ w0p, const float* __restrict__ b0,
        const unsigned short* __restrict__ w1T, const float* __restrict__ b1,
        const unsigned short* __restrict__ w2T, const float* __restrict__ b2,
        float* __restrict__ g) {
    __shared__ __align__(16) unsigned short hb[64 * 128];   // 16384 B, wave-private
    const int lane = threadIdx.x;
    const int n0   = blockIdx.x * 64;
    const int l31  = lane & 31;
    const int h    = lane >> 5;

    // graph ids + run-start mask (registers only)
    const int gi = batch[n0 + lane];
    const int gp = __shfl_up(gi, 1);
    const unsigned long long mask = __ballot((lane == 0) || (gi != gp));

    f32x16 acc[8];

    // swapped-C writeback: col=node (lane&31), row=of ((reg&3)+8*(reg>>2)+4*h)
    // packed 4 consecutive of per lane -> ushort4 store into swizzled hb
    auto writeback = [&](const float* __restrict__ bias) {
        #pragma unroll
        for (int mt = 0; mt < 4; ++mt) {
            #pragma unroll
            for (int g4 = 0; g4 < 4; ++g4) {
                const int of0 = mt*32 + 8*g4 + 4*h;
                const float4 bv = *reinterpret_cast<const float4*>(bias + of0);
                #pragma unroll
                for (int nt = 0; nt < 2; ++nt) {
                    const int node = nt*32 + l31;
                    const f32x16 A = acc[mt*2 + nt];
                    ushort4 s;
                    s.x = f2bf(fmaxf(A[g4*4+0] + bv.x, 0.f));
                    s.y = f2bf(fmaxf(A[g4*4+1] + bv.y, 0.f));
                    s.z = f2bf(fmaxf(A[g4*4+2] + bv.z, 0.f));
                    s.w = f2bf(fmaxf(A[g4*4+3] + bv.w, 0.f));
                    // of0 = (mt*4+g4)*8 + 4*h  -> chunk mt*4+g4, half h
                    *reinterpret_cast<ushort4*>(&hb[swz(node, mt*4 + g4) + h*4]) = s;
                }
            }
        }
    };

    // ---- layer 1 (swapped: A = w0p [of][k], B = x rows [node][k], K=16) ----
    {
        short8 af[4];
        #pragma unroll
        for (int mt = 0; mt < 4; ++mt)
            af[mt] = *reinterpret_cast<const short8*>(
                w0p + (mt*32 + l31) * 16 + h*8);
        short8 bf[2];
        #pragma unroll
        for (int nt = 0; nt < 2; ++nt) {
            const float4 xv = *reinterpret_cast<const float4*>(
                x + (size_t)(n0 + nt*32 + l31) * 4);
            short8 v = (short8){0,0,0,0,0,0,0,0};
            if (h == 0) {
                v[0] = (short)f2bf(xv.x); v[1] = (short)f2bf(xv.y);
                v[2] = (short)f2bf(xv.z); v[3] = (short)f2bf(xv.w);
            }
            bf[nt] = v;
        }
        #pragma unroll
        for (int t = 0; t < 8; ++t) acc[t] = (f32x16){};
        #pragma unroll
        for (int mt = 0; mt < 4; ++mt)
            #pragma unroll
            for (int nt = 0; nt < 2; ++nt)
                acc[mt*2 + nt] = __builtin_amdgcn_mfma_f32_32x32x16_bf16(
                    af[mt], bf[nt], acc[mt*2 + nt], 0, 0, 0);
    }
    writeback(b0);

    // ---- layer 2 (swapped: A = w1T [of][k], B = hb rows [node][k]) ----
    #pragma unroll
    for (int t = 0; t < 8; ++t) acc[t] = (f32x16){};
    #pragma unroll
    for (int ks = 0; ks < 8; ++ks) {
        short8 a[4], b[2];
        #pragma unroll
        for (int mt = 0; mt < 4; ++mt)
            a[mt] = *reinterpret_cast<const short8*>(
                w1T + (mt*32 + l31) * 128 + ks*16 + h*8);
        #pragma unroll
        for (int nt = 0; nt < 2; ++nt)
            b[nt] = *reinterpret_cast<const short8*>(&hb[swz(nt*32 + l31, ks*2 + h)]);
        #pragma unroll
        for (int mt = 0; mt < 4; ++mt)
            #pragma unroll
            for (int nt = 0; nt < 2; ++nt)
                acc[mt*2 + nt] = __builtin_amdgcn_mfma_f32_32x32x16_bf16(
                    a[mt], b[nt], acc[mt*2 + nt], 0, 0, 0);
    }
    writeback(b1);   // in-place safe: all LDS reads precede writes, DS is in-order

    // ---- layer 3 (normal: A = hb rows [node][k], B = w2T [of][k]) ----
    #pragma unroll
    for (int t = 0; t < 8; ++t) acc[t] = (f32x16){};
    #pragma unroll
    for (int ks = 0; ks < 8; ++ks) {
        short8 a[2], b[4];
        #pragma unroll
        for (int mtn = 0; mtn < 2; ++mtn)
            a[mtn] = *reinterpret_cast<const short8*>(&hb[swz(mtn*32 + l31, ks*2 + h)]);
        #pragma unroll
        for (int ntc = 0; ntc < 4; ++ntc)
            b[ntc] = *reinterpret_cast<const short8*>(
                w2T + (ntc*32 + l31) * 128 + ks*16 + h*8);
        #pragma unroll
        for (int mtn = 0; mtn < 2; ++mtn)
            #pragma unroll
            for (int ntc = 0; ntc < 4; ++ntc)
                acc[mtn*4 + ntc] = __builtin_amdgcn_mfma_f32_32x32x16_bf16(
                    a[mtn], b[ntc], acc[mtn*4 + ntc], 0, 0, 0);
    }

    // ---- epilogue: register segmented sum. C: col=of (l31), row=node ----
    float b2v[4];
    #pragma unroll
    for (int ntc = 0; ntc < 4; ++ntc) b2v[ntc] = b2[ntc*32 + l31];

    unsigned long long rem = mask & (mask - 1);
    int s = 0;
    while (true) {
        const int e = rem ? (int)__builtin_ctzll(rem) : 64;
        const int grun = __shfl(gi, s);
        const float cnt = (float)(e - s);
        float* gdst = g + (size_t)grun * 128;
        #pragma unroll
        for (int ntc = 0; ntc < 4; ++ntc) {
            float val = 0.f;
            #pragma unroll
            for (int mtn = 0; mtn < 2; ++mtn) {
                const f32x16 A = acc[mtn*4 + ntc];
                #pragma unroll
                for (int r = 0; r < 16; ++r) {
                    const int node = mtn*32 + (r & 3) + 8*(r >> 2) + 4*h;
                    const float inc = (node >= s && node < e) ? 1.f : 0.f;
                    val = fmaf(A[r], inc, val);
                }
            }
            val += __shfl_xor(val, 32);
            if (h == 0)
                atomicAdd(gdst + ntc*32 + l31, fmaf(cnt, b2v[ntc], val));
        }
        if (!rem) break;
        s = e;
        rem &= rem - 1;
    }
}

// ---- F head: fused 3 layers, 8 graphs/block, 512 blocks ----
__global__ __launch_bounds__(256) void head_kernel(
        const float* __restrict__ g,
        const float* __restrict__ fw0, const float* __restrict__ fb0,
        const float* __restrict__ fw1, const float* __restrict__ fb1,
        const float* __restrict__ fw2, const float* __restrict__ fb2,
        float* __restrict__ out) {
    __shared__ float gS[128 * GS];
    __shared__ float h1T[256 * GS];
    __shared__ float red[4][16];
    const int tid = threadIdx.x;
    const int g0  = blockIdx.x * 8;

    {
        const int gr = tid >> 5, k0 = (tid & 31) * 4;
        const float4 v = *reinterpret_cast<const float4*>(
            g + (size_t)(g0 + gr) * 128 + k0);
        gS[(k0+0)*GS + gr] = v.x; gS[(k0+1)*GS + gr] = v.y;
        gS[(k0+2)*GS + gr] = v.z; gS[(k0+3)*GS + gr] = v.w;
    }
    __syncthreads();

    float a1[8];
    #pragma unroll
    for (int i = 0; i < 8; ++i) a1[i] = 0.f;
    #pragma unroll 4
    for (int k = 0; k < 128; ++k) {
        const float w = fw0[k * 256 + tid];
        const f32x4 v0 = *reinterpret_cast<const f32x4*>(&gS[k*GS]);
        const f32x4 v1 = *reinterpret_cast<const f32x4*>(&gS[k*GS + 4]);
        #pragma unroll
        for (int j = 0; j < 4; ++j) {
            a1[j]     = fmaf(v0[j], w, a1[j]);
            a1[4 + j] = fmaf(v1[j], w, a1[4 + j]);
        }
    }
    {
        const float bb = fb0[tid];
        f32x4 s0, s1;
        #pragma unroll
        for (int j = 0; j < 4; ++j) {
            s0[j] = fmaxf(a1[j] + bb, 0.f);
            s1[j] = fmaxf(a1[4 + j] + bb, 0.f);
        }
        *reinterpret_cast<f32x4*>(&h1T[tid*GS])     = s0;
        *reinterpret_cast<f32x4*>(&h1T[tid*GS + 4]) = s1;
    }
    __syncthreads();

    float a2[8];
    #pragma unroll
    for (int i = 0; i < 8; ++i) a2[i] = 0.f;
    #pragma unroll 4
    for (int k = 0; k < 256; ++k) {
        const float w = fw1[k * 256 + tid];
        const f32x4 v0 = *reinterpret_cast<const f32x4*>(&h1T[k*GS]);
        const f32x4 v1 = *reinterpret_cast<const f32x4*>(&h1T[k*GS + 4]);
        #pragma unroll
        for (int j = 0; j < 4; ++j) {
            a2[j]     = fmaf(v0[j], w, a2[j]);
            a2[4 + j] = fmaf(v1[j], w, a2[4 + j]);
        }
    }

    float p[16];
    {
        const float bb  = fb1[tid];
        const float w2a = fw2[tid*2 + 0];
        const float w2b = fw2[tid*2 + 1];
        #pragma unroll
        for (int i = 0; i < 8; ++i) {
            const float h2 = fmaxf(a2[i] + bb, 0.f);
            p[i*2 + 0] = h2 * w2a;
            p[i*2 + 1] = h2 * w2b;
        }
    }
    #pragma unroll
    for (int i = 0; i < 16; ++i) {
        float v = p[i];
        v += __shfl_xor(v, 32); v += __shfl_xor(v, 16); v += __shfl_xor(v, 8);
        v += __shfl_xor(v, 4);  v += __shfl_xor(v, 2);  v += __shfl_xor(v, 1);
        p[i] = v;
    }
    if ((tid & 63) == 0) {
        #pragma unroll
        for (int i = 0; i < 16; ++i) red[tid >> 6][i] = p[i];
    }
    __syncthreads();
    if (tid < 16)
        out[g0*2 + tid] = red[0][tid] + red[1][tid] + red[2][tid] + red[3][tid]
                        + fb2[tid & 1];
}

extern "C" void kernel_launch(void* const* d_in, const int* in_sizes, int n_in,
                              void* d_out, int out_size, void* d_ws, size_t ws_size,
                              hipStream_t stream) {
    const float* x   = (const float*)d_in[0];
    // d_in[1] edge_index: mathematically dead (update() ignores aggr_out) — never read
    const int*   batch = (const int*)d_in[2];
    const float* w0  = (const float*)d_in[3];
    const float* b0  = (const float*)d_in[4];
    const float* w1  = (const float*)d_in[5];
    const float* b1  = (const float*)d_in[6];
    const float* w2  = (const float*)d_in[7];
    const float* b2  = (const float*)d_in[8];
    const float* fw0 = (const float*)d_in[9];
    const float* fb0 = (const float*)d_in[10];
    const float* fw1 = (const float*)d_in[11];
    const float* fb1 = (const float*)d_in[12];
    const float* fw2 = (const float*)d_in[13];
    const float* fb2 = (const float*)d_in[14];
    float* out = (float*)d_out;

    float* g = (float*)d_ws;                                        // 2 MB
    unsigned short* w1T = (unsigned short*)((char*)d_ws + (size_t)NGRAPHS * 128 * 4);
    unsigned short* w2T = w1T + 128 * 128;
    unsigned short* w0p = w2T + 128 * 128;                          // 4 KB

    (void)hipMemsetAsync(g, 0, (size_t)NGRAPHS * 128 * sizeof(float), stream);
    prep_weights<<<136, 256, 0, stream>>>(w0, w1, w2, w0p, w1T, w2T);
    phi_kernel<<<NNODES / 64, 64, 0, stream>>>(x, batch, w0p, b0, w1T, b1, w2T, b2, g);
    head_kernel<<<NGRAPHS / 8, 256, 0, stream>>>(g, fw0, fb0, fw1, fb1, fw2, fb2, out);
}